// Round 1
// baseline (254.646 us; speedup 1.0000x reference)
//
#include <hip/hip_runtime.h>
#include <math.h>

// Problem constants
#define B_   4
#define CIN  256
#define CK   128
#define HH   64
#define WW   64
#define NC   21
#define NTOT (B_*HH*WW)   // 16384

// workspace layout (float offsets). Requires ws_size >= ~18.3 MB.
#define OFF_WT   0                       // 2304*128 transposed conv1 weights [k][co]
#define SZ_WT    (2304*128)
#define OFF_PT   (OFF_WT + SZ_WT)        // [i][o] = -w/s
#define OFF_QT   (OFF_PT + CK*CK)        // [i][o] = -0.5*log2e/s^2
#define OFF_TT   (OFF_QT + CK*CK)        // [i][o] = t
#define OFF_BT   (OFF_TT + CK*CK)        // [i][o] = base_w
#define OFF_H    (OFF_BT + CK*CK)        // h (B,CK,H,W)  16384*128
#define OFF_K    (OFF_H + NTOT*CK)       // k (N,128)

// ---------------- Kernel 0: precompute transposes / folded params ----------
__global__ __launch_bounds__(256) void precompute_k(
    const float* __restrict__ w1, const float* __restrict__ ks,
    const float* __restrict__ kt, const float* __restrict__ kw,
    const float* __restrict__ kb, float* __restrict__ ws) {
  int tid = blockIdx.x * 256 + threadIdx.x;
  if (tid < 2304 * 128) {
    int k = tid >> 7, co = tid & 127;
    ws[OFF_WT + tid] = w1[co * 2304 + k];       // wT[k][co]
  } else if (tid < 2304 * 128 + CK * CK) {
    int j = tid - 2304 * 128;
    int i = j >> 7, o = j & 127;
    float s  = ks[o * 128 + i];
    float rs = 1.0f / s;
    ws[OFF_PT + j] = -rs * kw[o * 128 + i];
    ws[OFF_QT + j] = -0.7213475204444817f * rs * rs;  // -0.5*log2(e)*rs^2
    ws[OFF_TT + j] = kt[o * 128 + i];
    ws[OFF_BT + j] = kb[o * 128 + i];
  }
}

// ---------------- Kernel 1: conv1 3x3 + bias + ReLU ------------------------
// grid 512 = cohalf(2) * b(4) * ty(8) * tx(8); block 256.
// tile: 64 cout x 8y x 8x. Each thread: 2 cout x 1 y-row x 8 x = 16 accs.
__global__ __launch_bounds__(256) void conv1_relu_k(
    const float* __restrict__ x, const float* __restrict__ wTg,
    const float* __restrict__ b1, float* __restrict__ h) {
  int blk = blockIdx.x;
  int txb = blk & 7, tyb = (blk >> 3) & 7, bb = (blk >> 6) & 3, cohalf = blk >> 8;
  int co_base = cohalf * 64;
  int t  = threadIdx.x;
  int cg = t & 31;         // cout pair id
  int ry = t >> 5;         // 0..7 output row within tile
  int co_loc = cg * 2;

  __shared__ float in_t[16][10][12];   // [cin][y(10)][x(12 pad)] 7.7KB
  __shared__ float w_t[144 * 64];      // [cin*9+tap][co64] 36.9KB

  float acc[2][8];
#pragma unroll
  for (int a = 0; a < 2; a++)
#pragma unroll
    for (int xx = 0; xx < 8; xx++) acc[a][xx] = 0.f;

  int y0 = tyb * 8, x0 = txb * 8;

  for (int cc = 0; cc < 16; ++cc) {     // 16 cin-chunks of 16
    // ---- stage input tile (zero-padded halo) ----
    if (t < 160) {
      int cin_l = t / 10, yy = t - cin_l * 10;
      int gy = y0 + yy - 1;
      bool yok = (gy >= 0 && gy < 64);
      const float* src = &x[(((bb * CIN) + cc * 16 + cin_l) * 64 + gy) * 64];
#pragma unroll
      for (int c = 0; c < 10; c++) {
        int gx = x0 + c - 1;
        float v = (yok && gx >= 0 && gx < 64) ? src[gx] : 0.f;
        in_t[cin_l][yy][c] = v;
      }
    }
    // ---- stage weights: 144 rows x 64 couts ----
#pragma unroll
    for (int rep = 0; rep < 9; rep++) {
      int j = t + rep * 256;            // 0..2303, one float4 each
      int row = j >> 4, co4 = (j & 15) * 4;
      float4 wv = *(const float4*)&wTg[(cc * 144 + row) * 128 + co_base + co4];
      *(float4*)&w_t[row * 64 + co4] = wv;
    }
    __syncthreads();
    // ---- compute ----
#pragma unroll
    for (int ci = 0; ci < 16; ++ci) {
#pragma unroll
      for (int ky = 0; ky < 3; ++ky) {
        float row[10];
        const float* rp = &in_t[ci][ry + ky][0];
        *(float4*)&row[0] = *(const float4*)&rp[0];
        *(float4*)&row[4] = *(const float4*)&rp[4];
        *(float2*)&row[8] = *(const float2*)&rp[8];
#pragma unroll
        for (int kx = 0; kx < 3; ++kx) {
          float2 wv = *(const float2*)&w_t[(ci * 9 + ky * 3 + kx) * 64 + co_loc];
#pragma unroll
          for (int xx = 0; xx < 8; ++xx) {
            acc[0][xx] = fmaf(row[xx + kx], wv.x, acc[0][xx]);
            acc[1][xx] = fmaf(row[xx + kx], wv.y, acc[1][xx]);
          }
        }
      }
    }
    __syncthreads();
  }
  // ---- epilogue: bias + relu, store NCHW ----
#pragma unroll
  for (int a = 0; a < 2; a++) {
    int co = co_base + co_loc + a;
    float bz = b1[co];
    float outv[8];
#pragma unroll
    for (int xx = 0; xx < 8; ++xx) outv[xx] = fmaxf(acc[a][xx] + bz, 0.f);
    float* dst = &h[(((bb * CK + co) * 64 + y0 + ry) * 64) + x0];
    *(float4*)&dst[0] = *(float4*)&outv[0];
    *(float4*)&dst[4] = *(float4*)&outv[4];
  }
}

// ---------------- Kernel 2: Wav-KAN (DoG) + base ---------------------------
// grid 512 (32 rows each); block 256 = 16 o-groups x 16 n-groups.
// thread: 8 o x 2 n accumulators.
#define KAN1(hv, sv, Pp, Qq, Tt, Bb, a)                    \
  {                                                        \
    float d_ = (hv) - (Tt);                                \
    float e_ = exp2f((Qq) * d_ * d_);                      \
    a = fmaf(d_ * e_, (Pp), a);                            \
    a = fmaf((sv), (Bb), a);                               \
  }

__global__ __launch_bounds__(256) void wavkan_k(
    const float* __restrict__ h, const float* __restrict__ Pt,
    const float* __restrict__ Qt, const float* __restrict__ Tt,
    const float* __restrict__ Bt, float* __restrict__ kout) {
  int blk = blockIdx.x;
  int n0 = blk * 32;
  int bb = n0 >> 12;       // batch
  int s0 = n0 & 4095;      // spatial base
  int t  = threadIdx.x;
  int og = t & 15; int ob = og * 8;
  int ng = t >> 4; int ng2 = ng * 2;

  __shared__ float hsm[32][129];                  // 16.5KB
  __shared__ float Ps[16][128], Qs[16][128], Ts[16][128], Bs[16][128]; // 32KB

  // ---- stage h tile once: [32 n][128 i], transposed writes ----
  {
    int i = t & 127, part = t >> 7;
    const float* src = &h[((bb * CK + i) * 4096) + s0 + part * 16];
    float v[16];
    *(float4*)&v[0]  = *(const float4*)&src[0];
    *(float4*)&v[4]  = *(const float4*)&src[4];
    *(float4*)&v[8]  = *(const float4*)&src[8];
    *(float4*)&v[12] = *(const float4*)&src[12];
#pragma unroll
    for (int r = 0; r < 16; r++) hsm[part * 16 + r][i] = v[r];
  }

  float acc[2][8];
#pragma unroll
  for (int j = 0; j < 2; j++)
#pragma unroll
    for (int o = 0; o < 8; o++) acc[j][o] = 0.f;

  for (int ich = 0; ich < 8; ++ich) {
    int i0 = ich * 16;
    __syncthreads();   // protects hsm staging (first iter) / param reuse
    // ---- stage params chunk [16 i][128 o] x4 arrays ----
    {
      int idx = t * 8;
      int r = idx >> 7, c = idx & 127;
      int g = (i0 + r) * 128 + c;
      *(float4*)&Ps[r][c]     = *(const float4*)&Pt[g];
      *(float4*)&Ps[r][c + 4] = *(const float4*)&Pt[g + 4];
      *(float4*)&Qs[r][c]     = *(const float4*)&Qt[g];
      *(float4*)&Qs[r][c + 4] = *(const float4*)&Qt[g + 4];
      *(float4*)&Ts[r][c]     = *(const float4*)&Tt[g];
      *(float4*)&Ts[r][c + 4] = *(const float4*)&Tt[g + 4];
      *(float4*)&Bs[r][c]     = *(const float4*)&Bt[g];
      *(float4*)&Bs[r][c + 4] = *(const float4*)&Bt[g + 4];
    }
    __syncthreads();
    // ---- compute ----
#pragma unroll
    for (int il = 0; il < 16; ++il) {
      float ha = hsm[ng2][i0 + il];
      float hb = hsm[ng2 + 1][i0 + il];
      float sa = ha / (1.f + __expf(-ha));   // silu (h>=0 post-relu, safe)
      float sb = hb / (1.f + __expf(-hb));
#pragma unroll
      for (int q = 0; q < 2; ++q) {
        int oc = q * 4;
        float4 P4 = *(const float4*)&Ps[il][ob + oc];
        float4 Q4 = *(const float4*)&Qs[il][ob + oc];
        float4 T4 = *(const float4*)&Ts[il][ob + oc];
        float4 B4 = *(const float4*)&Bs[il][ob + oc];
        KAN1(ha, sa, P4.x, Q4.x, T4.x, B4.x, acc[0][oc + 0]);
        KAN1(hb, sb, P4.x, Q4.x, T4.x, B4.x, acc[1][oc + 0]);
        KAN1(ha, sa, P4.y, Q4.y, T4.y, B4.y, acc[0][oc + 1]);
        KAN1(hb, sb, P4.y, Q4.y, T4.y, B4.y, acc[1][oc + 1]);
        KAN1(ha, sa, P4.z, Q4.z, T4.z, B4.z, acc[0][oc + 2]);
        KAN1(hb, sb, P4.z, Q4.z, T4.z, B4.z, acc[1][oc + 2]);
        KAN1(ha, sa, P4.w, Q4.w, T4.w, B4.w, acc[0][oc + 3]);
        KAN1(hb, sb, P4.w, Q4.w, T4.w, B4.w, acc[1][oc + 3]);
      }
    }
  }
  // ---- store k rows ----
#pragma unroll
  for (int j = 0; j < 2; j++) {
    float* dst = &kout[(n0 + ng2 + j) * 128 + ob];
    *(float4*)&dst[0] = *(float4*)&acc[j][0];
    *(float4*)&dst[4] = *(float4*)&acc[j][4];
  }
}

// ---------------- Kernel 3: conv2 1x1 + bias -------------------------------
// grid 512 (32 rows each); block 256 = 32 n x 8 nc-groups; ncs {g, g+8, g+16}
__global__ __launch_bounds__(256) void conv2_k(
    const float* __restrict__ kin, const float* __restrict__ w2,
    const float* __restrict__ b2, float* __restrict__ out) {
  int blk = blockIdx.x;
  int n0 = blk * 32;
  int bb = n0 >> 12, s0 = n0 & 4095;
  int t = threadIdx.x;
  __shared__ float ksm[32][132];     // 16.9KB (132: b128-aligned rows)
  __shared__ float wsm[NC * 128];    // 10.5KB

  {
    int idx = t * 16;
    int n = idx >> 7, c = idx & 127;
    const float* src = &kin[(n0 + n) * 128 + c];
    *(float4*)&ksm[n][c]      = *(const float4*)&src[0];
    *(float4*)&ksm[n][c + 4]  = *(const float4*)&src[4];
    *(float4*)&ksm[n][c + 8]  = *(const float4*)&src[8];
    *(float4*)&ksm[n][c + 12] = *(const float4*)&src[12];
  }
  for (int j = t; j < NC * 32; j += 256)   // 672 float4s
    *(float4*)&wsm[j * 4] = *(const float4*)&w2[j * 4];
  __syncthreads();

  int n = t & 31, ncg = t >> 5;
  int nc0 = ncg, nc1 = ncg + 8, nc2 = ncg + 16;
  bool has2 = (nc2 < NC);
  float a0 = 0.f, a1 = 0.f, a2 = 0.f;
#pragma unroll
  for (int i4 = 0; i4 < 32; ++i4) {
    float4 k4 = *(const float4*)&ksm[n][i4 * 4];
    float4 wA = *(const float4*)&wsm[nc0 * 128 + i4 * 4];
    float4 wB = *(const float4*)&wsm[nc1 * 128 + i4 * 4];
    a0 += k4.x * wA.x + k4.y * wA.y + k4.z * wA.z + k4.w * wA.w;
    a1 += k4.x * wB.x + k4.y * wB.y + k4.z * wB.z + k4.w * wB.w;
    if (has2) {
      float4 wC = *(const float4*)&wsm[nc2 * 128 + i4 * 4];
      a2 += k4.x * wC.x + k4.y * wC.y + k4.z * wC.z + k4.w * wC.w;
    }
  }
  int sp = s0 + n;
  out[(bb * NC + nc0) * 4096 + sp] = a0 + b2[nc0];
  out[(bb * NC + nc1) * 4096 + sp] = a1 + b2[nc1];
  if (has2) out[(bb * NC + nc2) * 4096 + sp] = a2 + b2[nc2];
}

// ---------------- launch ---------------------------------------------------
extern "C" void kernel_launch(void* const* d_in, const int* in_sizes, int n_in,
                              void* d_out, int out_size, void* d_ws, size_t ws_size,
                              hipStream_t stream) {
  const float* x   = (const float*)d_in[0];
  const float* w1  = (const float*)d_in[1];
  const float* b1  = (const float*)d_in[2];
  const float* ks  = (const float*)d_in[3];
  const float* kt  = (const float*)d_in[4];
  const float* kw  = (const float*)d_in[5];
  const float* kb  = (const float*)d_in[6];
  const float* w2  = (const float*)d_in[7];
  const float* b2  = (const float*)d_in[8];
  float* out = (float*)d_out;
  float* ws  = (float*)d_ws;

  precompute_k<<<1408, 256, 0, stream>>>(w1, ks, kt, kw, kb, ws);
  conv1_relu_k<<<512, 256, 0, stream>>>(x, ws + OFF_WT, b1, ws + OFF_H);
  wavkan_k<<<512, 256, 0, stream>>>(ws + OFF_H, ws + OFF_PT, ws + OFF_QT,
                                    ws + OFF_TT, ws + OFF_BT, ws + OFF_K);
  conv2_k<<<512, 256, 0, stream>>>(ws + OFF_K, w2, b2, out);
}

// Round 2
// 167.356 us; speedup vs baseline: 1.5216x; 1.5216x over previous
//
#include <hip/hip_runtime.h>
#include <math.h>

typedef __attribute__((ext_vector_type(8))) short s16x8;
typedef __attribute__((ext_vector_type(4))) float f32x4;

#define LOG2E 1.4426950408889634f

// ---- workspace layout (float offsets), total 17.59 MB ----
#define OFF_XH   0           // xh bf16 NHWC [4][4096][256] = 2,097,152 floats; ALIASED later by k_wav f32 [16384][128]
#define OFF_WB   2097152     // conv1 weights bf16 MFMA layout [ch2][ck8][tap9][g4][co64][j8] = 147,456 floats
#define OFF_PT   2244608     // [i][o] = -w/s
#define OFF_QT   2260992     // [i][o] = -0.5*log2e/s^2
#define OFF_TT   2277376     // [i][o] = t
#define OFF_W2   2293760     // W2cat [21][256] = [w2 | w2@base_w]
#define OFF_H    2299136     // h f32 NHWC [16384][128]

// ---------------- transpose x: NCHW f32 -> NHWC bf16 -----------------------
__global__ __launch_bounds__(256) void transpose_x_k(
    const float* __restrict__ x, unsigned short* __restrict__ xh) {
  __shared__ float lsm[64][65];
  int blk = blockIdx.x;
  int pr = blk & 63, cib = (blk >> 6) & 3, bb = blk >> 8;
  int t = threadIdx.x;
  int sp0 = pr * 64;
  const float* src = x + (unsigned)(bb * 256 + cib * 64) * 4096 + sp0;
#pragma unroll
  for (int rr = 0; rr < 16; ++rr) {
    int idx = rr * 256 + t;
    int ci = idx >> 6, px = idx & 63;
    lsm[ci][px] = src[ci * 4096 + px];
  }
  __syncthreads();
#pragma unroll
  for (int rr = 0; rr < 16; ++rr) {
    int idx = rr * 256 + t;
    int px = idx >> 6, ci = idx & 63;
    unsigned u = __float_as_uint(lsm[ci][px]);
    xh[(unsigned)(bb * 4096 + sp0 + px) * 256 + cib * 64 + ci] =
        (unsigned short)((u + 0x7FFF + ((u >> 16) & 1)) >> 16);
  }
}

// ---------------- prep weights: Wb bf16, folded KAN params, W2 copy --------
__global__ __launch_bounds__(256) void prep_w_k(
    const float* __restrict__ w1, const float* __restrict__ ks,
    const float* __restrict__ kt, const float* __restrict__ kw,
    const float* __restrict__ w2, float* __restrict__ ws) {
  int tid = blockIdx.x * 256 + threadIdx.x;
  unsigned short* Wb = (unsigned short*)(ws + OFF_WB);
  if (tid < 294912) {
    int j = tid & 7, co = (tid >> 3) & 63, g = (tid >> 9) & 3, r = tid >> 11;
    int t9 = r % 9, q = r / 9, ck = q & 7, chh = q >> 3;
    int ci = ck * 32 + g * 8 + j, cog = chh * 64 + co;
    unsigned u = __float_as_uint(w1[(unsigned)(cog * 256 + ci) * 9 + t9]);
    Wb[tid] = (unsigned short)((u + 0x7FFF + ((u >> 16) & 1)) >> 16);
  } else if (tid < 294912 + 16384) {
    int i2 = tid - 294912;
    int i = i2 >> 7, o = i2 & 127;
    float rs = 1.f / ks[o * 128 + i];
    ws[OFF_PT + i2] = -rs * kw[o * 128 + i];
    ws[OFF_QT + i2] = -0.7213475204444817f * rs * rs;
    ws[OFF_TT + i2] = kt[o * 128 + i];
  } else if (tid < 294912 + 16384 + 2688) {
    int i3 = tid - 294912 - 16384;
    int nc = i3 >> 7, k = i3 & 127;
    ws[OFF_W2 + nc * 256 + k] = w2[nc * 128 + k];
  }
}

// W2B[nc][i] = sum_o w2[nc][o] * base_w[o][i]  (folds base branch into conv2)
__global__ __launch_bounds__(128) void w2b_k(
    const float* __restrict__ w2, const float* __restrict__ bw,
    float* __restrict__ w2c) {
  int nc = blockIdx.x, i = threadIdx.x;
  float acc = 0.f;
  for (int o = 0; o < 128; ++o)
    acc = fmaf(w2[nc * 128 + o], bw[o * 128 + i], acc);
  w2c[nc * 256 + 128 + i] = acc;
}

// ---------------- conv1 3x3 as bf16 MFMA implicit GEMM ---------------------
// grid 256 = bb(4) x ytile(32, 2 rows) x cohalf(2); block 256 = 4 waves.
// block tile 128M(2y x 64x) x 64N; wave tile 64x32 (Mr=4, Nr=2), mfma 16x16x32.
__global__ __launch_bounds__(256) void conv1_mfma_k(
    const unsigned short* __restrict__ xh, const unsigned short* __restrict__ Wb,
    const float* __restrict__ b1, float* __restrict__ h) {
  __shared__ unsigned short Asm[4 * 66 * 40];  // [yrow4][x66][ci 32 pad40] 21.1KB
  __shared__ unsigned short Bsm[18432];        // [tap9][g4][co64][j8]      36.9KB
  int blk = blockIdx.x;
  int ch = blk & 1, yt = (blk >> 1) & 31, bb = blk >> 6;
  int y0 = yt * 2;
  int t = threadIdx.x;
  int wave = t >> 6, lane = t & 63;
  int wm = wave >> 1, wn = wave & 1;
  int l15 = lane & 15, lg = lane >> 4;

  if (t < 8) {  // zero x-halo columns (stay zero across chunks)
    int r = t >> 1, xl = (t & 1) * 65;
    float4 z = {0, 0, 0, 0};
    float4* p = (float4*)&Asm[(r * 66 + xl) * 40];
    p[0] = z; p[1] = z; p[2] = z; p[3] = z; p[4] = z;
  }

  f32x4 acc[4][2];
  f32x4 zz = {0.f, 0.f, 0.f, 0.f};
#pragma unroll
  for (int f = 0; f < 4; ++f) { acc[f][0] = zz; acc[f][1] = zz; }

  int r_st = t >> 6, x_st = t & 63;
  int gy = y0 - 1 + r_st;
  bool yok = (gy >= 0) & (gy < 64);
  const unsigned short* asrc = xh + (unsigned)(bb * 4096 + gy * 64 + x_st) * 256;
  unsigned short* adst = &Asm[(r_st * 66 + x_st + 1) * 40];
  const unsigned short* bslab = Wb + ch * 8 * 18432;

  for (int ck = 0; ck < 8; ++ck) {
    float4 v0 = {0, 0, 0, 0}, v1 = v0, v2 = v0, v3 = v0;
    if (yok) {
      const float4* s = (const float4*)(asrc + ck * 32);
      v0 = s[0]; v1 = s[1]; v2 = s[2]; v3 = s[3];
    }
    { float4* d = (float4*)adst; d[0] = v0; d[1] = v1; d[2] = v2; d[3] = v3; }
    {
      const float4* s = (const float4*)(bslab + ck * 18432);
      float4* d = (float4*)Bsm;
#pragma unroll
      for (int j = 0; j < 9; ++j) d[j * 256 + t] = s[j * 256 + t];
    }
    __syncthreads();
#pragma unroll
    for (int t9 = 0; t9 < 9; ++t9) {
      int ky = t9 / 3, kx = t9 % 3;
      s16x8 a[4], b[2];
      int abase = ((wm + ky) * 66 + l15 + kx) * 40 + lg * 8;
#pragma unroll
      for (int f = 0; f < 4; ++f)
        a[f] = *(const s16x8*)&Asm[abase + f * 640];
#pragma unroll
      for (int n = 0; n < 2; ++n)
        b[n] = *(const s16x8*)&Bsm[((t9 * 4 + lg) * 64 + wn * 32 + n * 16 + l15) * 8];
#pragma unroll
      for (int f = 0; f < 4; ++f)
#pragma unroll
        for (int n = 0; n < 2; ++n)
          acc[f][n] = __builtin_amdgcn_mfma_f32_16x16x32_bf16(a[f], b[n], acc[f][n], 0, 0, 0);
    }
    __syncthreads();
  }
  // epilogue: bias + relu, store h NHWC f32
#pragma unroll
  for (int n = 0; n < 2; ++n) {
    int co = ch * 64 + wn * 32 + n * 16 + l15;
    float bz = b1[co];
#pragma unroll
    for (int f = 0; f < 4; ++f) {
      int xbase = f * 16 + lg * 4;
      float* dst = h + (unsigned)(bb * 4096 + (y0 + wm) * 64 + xbase) * 128 + co;
#pragma unroll
      for (int r = 0; r < 4; ++r) {
        float v = acc[f][n][r] + bz;
        dst[r * 128] = v > 0.f ? v : 0.f;
      }
    }
  }
}

// ---------------- Wav-KAN, DoG term only -----------------------------------
// grid 256 (64 n-rows each); block 256 = 16 og x 16 ng; thread: 8 o x 4 n.
__global__ __launch_bounds__(256) void wavkan_k(
    const float* __restrict__ h, const float* __restrict__ PT,
    const float* __restrict__ QT, const float* __restrict__ TT,
    float* __restrict__ kwout) {
  __shared__ float hsm[64][132];      // 33.8KB
  __shared__ float Par[3][16][128];   // 24.6KB  (P,Q,T per 16-i chunk)
  int n0 = blockIdx.x * 64;
  int t = threadIdx.x;
  int og = t & 15, ng = t >> 4;
  int ob = og * 8, nb = ng * 4;

#pragma unroll
  for (int rr = 0; rr < 8; ++rr) {
    int idx4 = rr * 256 + t;
    int row = idx4 >> 5, c4 = (idx4 & 31) * 4;
    *(float4*)&hsm[row][c4] = *(const float4*)&h[(unsigned)(n0 + row) * 128 + c4];
  }

  float acc[4][8];
#pragma unroll
  for (int j = 0; j < 4; ++j)
#pragma unroll
    for (int o = 0; o < 8; ++o) acc[j][o] = 0.f;

  for (int ich = 0; ich < 8; ++ich) {
    int i0 = ich * 16;
    __syncthreads();
#pragma unroll
    for (int a = 0; a < 6; ++a) {
      int idx4 = a * 256 + t;
      int arr = idx4 >> 9, rem = idx4 & 511;
      int r = rem >> 5, c4 = (rem & 31) * 4;
      const float* sp = arr == 0 ? PT : (arr == 1 ? QT : TT);
      *(float4*)&Par[arr][r][c4] = *(const float4*)&sp[(unsigned)(i0 + r) * 128 + c4];
    }
    __syncthreads();
#pragma unroll
    for (int il = 0; il < 16; ++il) {
      int i = i0 + il;
      float hv[4];
#pragma unroll
      for (int j = 0; j < 4; ++j) hv[j] = hsm[nb + j][i];
#pragma unroll
      for (int q = 0; q < 2; ++q) {
        float4 P4 = *(const float4*)&Par[0][il][ob + q * 4];
        float4 Q4 = *(const float4*)&Par[1][il][ob + q * 4];
        float4 T4 = *(const float4*)&Par[2][il][ob + q * 4];
#pragma unroll
        for (int j = 0; j < 4; ++j) {
          float d, e;
          d = hv[j] - T4.x; e = __builtin_amdgcn_exp2f(Q4.x * d * d);
          acc[j][q * 4 + 0] = fmaf(d * e, P4.x, acc[j][q * 4 + 0]);
          d = hv[j] - T4.y; e = __builtin_amdgcn_exp2f(Q4.y * d * d);
          acc[j][q * 4 + 1] = fmaf(d * e, P4.y, acc[j][q * 4 + 1]);
          d = hv[j] - T4.z; e = __builtin_amdgcn_exp2f(Q4.z * d * d);
          acc[j][q * 4 + 2] = fmaf(d * e, P4.z, acc[j][q * 4 + 2]);
          d = hv[j] - T4.w; e = __builtin_amdgcn_exp2f(Q4.w * d * d);
          acc[j][q * 4 + 3] = fmaf(d * e, P4.w, acc[j][q * 4 + 3]);
        }
      }
    }
  }
#pragma unroll
  for (int j = 0; j < 4; ++j) {
    float* dst = kwout + (unsigned)(n0 + nb + j) * 128 + ob;
    *(float4*)&dst[0] = *(float4*)&acc[j][0];
    *(float4*)&dst[4] = *(float4*)&acc[j][4];
  }
}

// ---------------- conv2 1x1, K=256 ([k_wav | silu(h)]) ---------------------
__global__ __launch_bounds__(256) void conv2_k(
    const float* __restrict__ kwv, const float* __restrict__ h,
    const float* __restrict__ w2c, const float* __restrict__ b2,
    float* __restrict__ out) {
  __shared__ float ksm[32][260];    // 33.3KB
  __shared__ float wsm[21 * 256];   // 21.5KB
  int n0 = blockIdx.x * 32;
  int t = threadIdx.x;
#pragma unroll
  for (int rr = 0; rr < 4; ++rr) {
    int idx4 = rr * 256 + t;
    int row = idx4 >> 5, c4 = (idx4 & 31) * 4;
    *(float4*)&ksm[row][c4] = *(const float4*)&kwv[(unsigned)(n0 + row) * 128 + c4];
    float4 v = *(const float4*)&h[(unsigned)(n0 + row) * 128 + c4];
    float4 s;
    s.x = v.x * __builtin_amdgcn_rcpf(1.f + __builtin_amdgcn_exp2f(-LOG2E * v.x));
    s.y = v.y * __builtin_amdgcn_rcpf(1.f + __builtin_amdgcn_exp2f(-LOG2E * v.y));
    s.z = v.z * __builtin_amdgcn_rcpf(1.f + __builtin_amdgcn_exp2f(-LOG2E * v.z));
    s.w = v.w * __builtin_amdgcn_rcpf(1.f + __builtin_amdgcn_exp2f(-LOG2E * v.w));
    *(float4*)&ksm[row][128 + c4] = s;
  }
  for (int j = t; j < 1344; j += 256)
    *(float4*)&wsm[j * 4] = *(const float4*)&w2c[j * 4];
  __syncthreads();

  int n = t & 31, ncg = t >> 5;
  float a0 = 0.f, a1 = 0.f, a2 = 0.f;
  bool has2 = ncg < 5;
#pragma unroll
  for (int i4 = 0; i4 < 64; ++i4) {
    float4 k4 = *(const float4*)&ksm[n][i4 * 4];
    float4 wA = *(const float4*)&wsm[ncg * 256 + i4 * 4];
    float4 wB = *(const float4*)&wsm[(ncg + 8) * 256 + i4 * 4];
    a0 += k4.x * wA.x + k4.y * wA.y + k4.z * wA.z + k4.w * wA.w;
    a1 += k4.x * wB.x + k4.y * wB.y + k4.z * wB.z + k4.w * wB.w;
    if (has2) {
      float4 wC = *(const float4*)&wsm[(ncg + 16) * 256 + i4 * 4];
      a2 += k4.x * wC.x + k4.y * wC.y + k4.z * wC.z + k4.w * wC.w;
    }
  }
  int gn = n0 + n, bb = gn >> 12, sp = gn & 4095;
  out[(unsigned)(bb * 21 + ncg) * 4096 + sp] = a0 + b2[ncg];
  out[(unsigned)(bb * 21 + ncg + 8) * 4096 + sp] = a1 + b2[ncg + 8];
  if (has2) out[(unsigned)(bb * 21 + ncg + 16) * 4096 + sp] = a2 + b2[ncg + 16];
}

// ---------------- launch ---------------------------------------------------
extern "C" void kernel_launch(void* const* d_in, const int* in_sizes, int n_in,
                              void* d_out, int out_size, void* d_ws, size_t ws_size,
                              hipStream_t stream) {
  const float* x  = (const float*)d_in[0];
  const float* w1 = (const float*)d_in[1];
  const float* b1 = (const float*)d_in[2];
  const float* ks = (const float*)d_in[3];
  const float* kt = (const float*)d_in[4];
  const float* kw = (const float*)d_in[5];
  const float* kb = (const float*)d_in[6];
  const float* w2 = (const float*)d_in[7];
  const float* b2 = (const float*)d_in[8];
  float* out = (float*)d_out;
  float* ws  = (float*)d_ws;

  transpose_x_k<<<1024, 256, 0, stream>>>(x, (unsigned short*)(ws + OFF_XH));
  prep_w_k<<<1227, 256, 0, stream>>>(w1, ks, kt, kw, w2, ws);
  w2b_k<<<21, 128, 0, stream>>>(w2, kb, ws + OFF_W2);
  conv1_mfma_k<<<256, 256, 0, stream>>>((const unsigned short*)(ws + OFF_XH),
                                        (const unsigned short*)(ws + OFF_WB),
                                        b1, ws + OFF_H);
  wavkan_k<<<256, 256, 0, stream>>>(ws + OFF_H, ws + OFF_PT, ws + OFF_QT,
                                    ws + OFF_TT, ws + OFF_XH /* k_wav alias */);
  conv2_k<<<512, 256, 0, stream>>>(ws + OFF_XH, ws + OFF_H, ws + OFF_W2, b2, out);
}